// Round 2
// baseline (3082.661 us; speedup 1.0000x reference)
//
#include <hip/hip_runtime.h>
#include <hip/hip_bf16.h>

#define NN 512
#define NB 32
#define NPANELS 16
#define BDIM 256
#define PF_BDIM 512
#define LB_BDIM 256

// ---------------- ws layout (float offsets) ----------------
// A    : [0,      262144)   512x512 row-major working copy
// V    : [262144, 524288)   16 panels x (512x32 row-major, rows local to k0)
// tau  : [524288, 524800)   (unused now, offsets kept)
// T    : [524800, 541184)   16 x 32x32 (row-major, upper tri, zeros below)
// Q    : [541184, 803328)   512x512 fp32 row-major
// Qbf  : [803328, 934400)   512x512 bf16 (ushort)

__device__ inline unsigned short f2bf(float x) {
    unsigned int u = __float_as_uint(x);
    return (unsigned short)((u + 0x7FFFu + ((u >> 16) & 1u)) >> 16);  // RNE
}

__global__ __launch_bounds__(BDIM)
void prep_kernel(const float* __restrict__ W, float* __restrict__ A, float* __restrict__ Q)
{
    int idx = blockIdx.x * BDIM + threadIdx.x;
    if (idx < NN * NN) {
        A[idx] = W[idx] + 1e-8f;
        int r = idx >> 9, c = idx & (NN - 1);
        Q[idx] = (r == c) ? 1.0f : 0.0f;
    }
}

// Panel factorization, 512 threads. Per column: 2 full-L passes (raw dot, update)
// + 4 barriers. Scale of pivot col runs on threads 32..511 during the 32-thread
// reduce; norm of col c+1 is fused into col c's update; dlarft fused as before.
// Identical arithmetic to LAPACK slarfg/larft convention.
__global__ __launch_bounds__(PF_BDIM)
void panel_fact(float* __restrict__ A, float* __restrict__ Vbuf,
                float* __restrict__ Tbuf, int p)
{
    const int k0 = p * NB;
    const int L  = NN - k0;               // multiple of 32
    const int LP = L + 1;                 // odd column stride (bank-friendly)
    __shared__ float sP[NB * (NN + 1)];   // 64.1 KB max
    __shared__ float red[PF_BDIM];
    __shared__ float red2[16];
    __shared__ float wbuf[NB];
    __shared__ float sdot[NB];
    __shared__ float sc[2];
    __shared__ float Tt[NB][NB];

    const int t = threadIdx.x;
    const int r = t >> 5;                 // 0..15 row group
    const int j = t & 31;                 // column within panel

    for (int idx = t; idx < L * NB; idx += PF_BDIM) {
        int i = idx >> 5, jj = idx & 31;
        sP[jj * LP + i] = A[(k0 + i) * NN + (k0 + jj)];
    }
    __syncthreads();

    // initial norm^2 of col 0 below diagonal (only col 0 needs a standalone pass)
    {
        float part = 0.f;
        for (int i = 1 + t; i < L; i += PF_BDIM) {
            float x = sP[i];
            part += x * x;
        }
        #pragma unroll
        for (int off = 32; off > 0; off >>= 1)
            part += __shfl_down(part, off, 64);
        if ((t & 63) == 0) red2[t >> 6] = part;
    }
    __syncthreads();

    for (int c = 0; c < NB; ++c) {
        // ---- scalar phase: Householder scalars from (fused) norm ----
        if (t == 0) {
            int np = (c == 0) ? 8 : 16;
            float xn2 = 0.f;
            for (int g = 0; g < np; ++g) xn2 += red2[g];
            float alpha = sP[c * LP + c];
            float tc, inv;
            if (xn2 <= 0.f) { tc = 0.f; inv = 0.f; }       // H = I (xnorm==0 path)
            else {
                float nrm  = sqrtf(alpha * alpha + xn2);
                float beta = (alpha >= 0.f) ? -nrm : nrm;  // -sign(alpha)*||.||
                tc  = (beta - alpha) / beta;
                inv = 1.f / (alpha - beta);
            }
            sc[0] = tc; sc[1] = inv;
        }
        __syncthreads();                                   // B1
        const float tc = sc[0], inv = sc[1];

        // ---- dot phase on RAW pivot column: D_j = sum_{i>c} rawc[i]*col_j[i] ----
        {
            float acc = 0.f;
            if (j != c) {
                #pragma unroll 4
                for (int i = c + 1 + r; i < L; i += 16)
                    acc += sP[c * LP + i] * sP[j * LP + i];
            }
            red[t] = acc;
        }
        __syncthreads();                                   // B2

        // ---- reduce (t<32) in parallel with scaling pivot column (t>=32) ----
        if (t < NB) {
            if (t != c) {
                float s = 0.f;
                #pragma unroll
                for (int g = 0; g < 16; ++g) s += red[g * NB + t];
                float val = sP[t * LP + c] + inv * s;      // adds the v_c[c]=1 row term
                if (t > c) wbuf[t] = tc * val;             // w_j
                else       sdot[t] = val;                  // S[t][c] for dlarft
            }
        } else {
            for (int i = t - NB; i < L; i += PF_BDIM - NB) {
                float x = sP[c * LP + i];
                sP[c * LP + i] = (i > c) ? x * inv : (i == c ? 1.0f : 0.0f);
            }
        }
        __syncthreads();                                   // B3

        // ---- update (j>c), with norm of col c+1 fused; dlarft col c on r==15 ----
        if (j > c) {
            float wv = wbuf[j];
            if (j == c + 1) {
                float nacc = 0.f;
                #pragma unroll 4
                for (int i = c + 1 + r; i < L; i += 16) {
                    float nv = sP[j * LP + i] - sP[c * LP + i] * wv;
                    sP[j * LP + i] = nv;
                    if (i > c + 1) nacc += nv * nv;
                }
                red2[r] = nacc;
            } else {
                #pragma unroll 4
                for (int i = c + 1 + r; i < L; i += 16)
                    sP[j * LP + i] -= sP[c * LP + i] * wv;
            }
        }
        if (r == 15) {
            if (j < c) {
                float s = 0.f;
                for (int l = j; l < c; ++l) s += Tt[j][l] * sdot[l];
                Tt[j][c] = -tc * s;
            } else if (j == c) {
                Tt[c][c] = tc;
            }
        }
        __syncthreads();                                   // B4
    }

    // ---- write V (unit-lower, zeros above: guaranteed by per-column scaling) ----
    for (int idx = t; idx < L * NB; idx += PF_BDIM) {
        int i = idx >> 5, jj = idx & 31;
        Vbuf[p * (NN * NB) + idx] = sP[jj * LP + i];
    }
    // ---- write T (upper tri, zeros below) ----
    for (int q = t; q < NB * NB; q += PF_BDIM) {
        int a = q >> 5, b = q & 31;
        Tbuf[p * (NB * NB) + q] = (a <= b) ? Tt[a][b] : 0.0f;
    }
}

// C[k0: , colStart:512] = (I - V * Top * V^T) C ; Top = T^T if transT else T.
// 256 threads: 32 col-pair lanes x 8 row chunks; 2 columns/thread halves the
// LDS V-broadcast instruction count. Optionally emits bf16 copy (fused cast_q).
__global__ __launch_bounds__(LB_BDIM)
void larfb_kernel(float* __restrict__ C, const float* __restrict__ Vbuf,
                  const float* __restrict__ Tbuf, int p, int colStart, int transT,
                  int emitBf, unsigned short* __restrict__ Qbf)
{
    const int k0 = p * NB;
    const int L  = NN - k0;
    const float* Vp = Vbuf + p * (NN * NB);
    const float* Tp = Tbuf + p * (NB * NB);

    __shared__ float sT[NB * NB];                      // 4 KB
    __shared__ __align__(16) float Vs[NN * NB];        // 64 KB (L*NB used)
    __shared__ float red[8][64][NB + 1];               // 67.6 KB, stride-33
    __shared__ float w2s[64][NB + 1];                  // 8.4 KB

    const int t    = threadIdx.x;
    const int w    = t >> 5;           // row chunk (0..7)
    const int cp   = t & 31;           // column pair
    const int col0 = colStart + blockIdx.x * 64 + 2 * cp;
    const bool valid = col0 < NN;      // col0 even, NN even -> pairwise validity

    for (int q = t; q < NB * NB; q += LB_BDIM) sT[q] = Tp[q];
    {
        const int nv4 = (L * NB) >> 2;
        const float4* Vp4 = (const float4*)Vp;
        float4* Vs4 = (float4*)Vs;
        for (int q = t; q < nv4; q += LB_BDIM) Vs4[q] = Vp4[q];
    }
    __syncthreads();

    // pass 1: y[m] partials for two columns, rows i = w, w+8, ...
    float y0[NB], y1[NB];
    #pragma unroll
    for (int m = 0; m < NB; ++m) { y0[m] = 0.f; y1[m] = 0.f; }
    if (valid) {
        #pragma unroll 2
        for (int i = w; i < L; i += 8) {
            float2 c2 = *(const float2*)(C + (long)(k0 + i) * NN + col0);
            const float4* vr = (const float4*)(Vs + i * NB);
            #pragma unroll
            for (int q4 = 0; q4 < 8; ++q4) {
                float4 v = vr[q4];
                y0[4*q4+0] += v.x * c2.x;  y1[4*q4+0] += v.x * c2.y;
                y0[4*q4+1] += v.y * c2.x;  y1[4*q4+1] += v.y * c2.y;
                y0[4*q4+2] += v.z * c2.x;  y1[4*q4+2] += v.z * c2.y;
                y0[4*q4+3] += v.w * c2.x;  y1[4*q4+3] += v.w * c2.y;
            }
        }
    }
    #pragma unroll
    for (int m = 0; m < NB; ++m) {
        red[w][2*cp][m]   = y0[m];
        red[w][2*cp+1][m] = y1[m];
    }
    __syncthreads();
    // sum 8 row-chunk partials -> red[0][jl][m]
    {
        int jl = t & 63, m0 = (t >> 6) * 8;
        #pragma unroll
        for (int mm = 0; mm < 8; ++mm) {
            int m = m0 + mm;
            float s = red[0][jl][m];
            #pragma unroll
            for (int g = 1; g < 8; ++g) s += red[g][jl][m];
            red[0][jl][m] = s;
        }
    }
    __syncthreads();
    // w2 = Top @ y per column
    {
        int jl = t & 63, m0 = (t >> 6) * 8;
        #pragma unroll
        for (int mm = 0; mm < 8; ++mm) {
            int m = m0 + mm;
            float s = 0.f;
            #pragma unroll
            for (int l = 0; l < NB; ++l) {
                float tv = transT ? sT[l * NB + m] : sT[m * NB + l];
                s += tv * red[0][jl][l];
            }
            w2s[jl][m] = s;
        }
    }
    __syncthreads();
    // pass 2: C -= V @ w2 (two columns); optional fused bf16 emit
    if (valid) {
        float w20[NB], w21[NB];
        #pragma unroll
        for (int m = 0; m < NB; ++m) { w20[m] = w2s[2*cp][m]; w21[m] = w2s[2*cp+1][m]; }
        #pragma unroll 2
        for (int i = w; i < L; i += 8) {
            const float4* vr = (const float4*)(Vs + i * NB);
            float u0 = 0.f, u1 = 0.f;
            #pragma unroll
            for (int q4 = 0; q4 < 8; ++q4) {
                float4 v = vr[q4];
                u0 += v.x * w20[4*q4+0] + v.y * w20[4*q4+1]
                    + v.z * w20[4*q4+2] + v.w * w20[4*q4+3];
                u1 += v.x * w21[4*q4+0] + v.y * w21[4*q4+1]
                    + v.z * w21[4*q4+2] + v.w * w21[4*q4+3];
            }
            float2* cptr = (float2*)(C + (long)(k0 + i) * NN + col0);
            float2 old = *cptr;
            old.x -= u0; old.y -= u1;
            *cptr = old;
            if (emitBf) {
                ushort2 b; b.x = f2bf(old.x); b.y = f2bf(old.y);
                *(ushort2*)(Qbf + (long)(k0 + i) * NN + col0) = b;
            }
        }
    }
}

// ---------------- GEMM: out(131072x512) = in(131072x512 fp32->bf16) @ Qbf^T ----------------
typedef __bf16 bf16x8 __attribute__((ext_vector_type(8)));
typedef float  f32x4  __attribute__((ext_vector_type(4)));

#define BM 128
#define BN 128
#define BK 32
#define AST 40   // padded LDS row stride (shorts): 80 B -> rows walk all 8 16B bank slots

__global__ __launch_bounds__(BDIM)
void gemm_kernel(const float* __restrict__ Ain, const unsigned short* __restrict__ Bt,
                 float* __restrict__ Cout)
{
    __shared__ __align__(16) unsigned short As[BM * AST];  // 10.2 KB
    __shared__ __align__(16) unsigned short Bs[BN * AST];  // 10.2 KB

    const int t   = threadIdx.x;
    // XCD-aware swizzle (grid=4096, %8==0)
    const int bid = (blockIdx.x >> 3) + (blockIdx.x & 7) * (4096 / 8);
    const int nt  = bid & 3;
    const int mt  = bid >> 2;
    const int m0  = mt * BM;
    const int n0  = nt * BN;

    const int lane = t & 63;
    const int wave = t >> 6;
    const int wm = wave >> 1, wn = wave & 1;

    f32x4 acc[4][4];
    #pragma unroll
    for (int a = 0; a < 4; ++a)
        #pragma unroll
        for (int b = 0; b < 4; ++b) acc[a][b] = (f32x4){0.f, 0.f, 0.f, 0.f};

    const int mrow_f = lane & 15;
    const int koff   = (lane >> 4) * 8;

    for (int kk = 0; kk < NN; kk += BK) {
        // stage A tile: 128x32 fp32 -> bf16 (fused convert), padded stride
        #pragma unroll
        for (int q = 0; q < 4; ++q) {
            int pidx = t + q * BDIM;           // 0..1023 float4s
            int mrow = pidx >> 3;
            int kq   = pidx & 7;
            const float4 a4 = *(const float4*)(Ain + (long)(m0 + mrow) * NN + kk + kq * 4);
            ushort4 b4;
            b4.x = f2bf(a4.x); b4.y = f2bf(a4.y); b4.z = f2bf(a4.z); b4.w = f2bf(a4.w);
            *(ushort4*)(&As[mrow * AST + kq * 4]) = b4;
        }
        // stage B tile: 128x32 bf16 straight copy, padded stride
        #pragma unroll
        for (int q = 0; q < 2; ++q) {
            int pidx = t + q * BDIM;           // 0..511 16B chunks
            int nrow = pidx >> 2;
            int k8   = pidx & 3;
            float4 raw = *(const float4*)(Bt + (long)(n0 + nrow) * NN + kk + k8 * 8);
            *(float4*)(&Bs[nrow * AST + k8 * 8]) = raw;
        }
        __syncthreads();

        bf16x8 af[4], bfr[4];
        #pragma unroll
        for (int a = 0; a < 4; ++a)
            af[a] = *(const bf16x8*)(&As[(wm * 64 + a * 16 + mrow_f) * AST + koff]);
        #pragma unroll
        for (int b = 0; b < 4; ++b)
            bfr[b] = *(const bf16x8*)(&Bs[(wn * 64 + b * 16 + mrow_f) * AST + koff]);
        #pragma unroll
        for (int a = 0; a < 4; ++a)
            #pragma unroll
            for (int b = 0; b < 4; ++b)
                acc[a][b] = __builtin_amdgcn_mfma_f32_16x16x32_bf16(af[a], bfr[b], acc[a][b], 0, 0, 0);
        __syncthreads();
    }

    #pragma unroll
    for (int a = 0; a < 4; ++a) {
        int rbase = m0 + wm * 64 + a * 16 + (lane >> 4) * 4;
        #pragma unroll
        for (int b = 0; b < 4; ++b) {
            int cidx = n0 + wn * 64 + b * 16 + (lane & 15);
            #pragma unroll
            for (int r = 0; r < 4; ++r)
                Cout[(long)(rbase + r) * NN + cidx] = acc[a][b][r];
        }
    }
}

extern "C" void kernel_launch(void* const* d_in, const int* in_sizes, int n_in,
                              void* d_out, int out_size, void* d_ws, size_t ws_size,
                              hipStream_t stream)
{
    const float* inp = (const float*)d_in[0];
    const float* wgt = (const float*)d_in[1];
    float* ws  = (float*)d_ws;
    float* A   = ws;
    float* V   = ws + 262144;
    float* T   = ws + 524800;
    float* Q   = ws + 541184;
    unsigned short* Qbf = (unsigned short*)(ws + 803328);
    float* out = (float*)d_out;

    prep_kernel<<<(NN * NN + BDIM - 1) / BDIM, BDIM, 0, stream>>>(wgt, A, Q);

    for (int p = 0; p < NPANELS; ++p) {
        panel_fact<<<1, PF_BDIM, 0, stream>>>(A, V, T, p);
        int colStart = p * NB + NB;
        int nc = NN - colStart;
        if (nc > 0)
            larfb_kernel<<<(nc + 63) / 64, LB_BDIM, 0, stream>>>(A, V, T, p, colStart, 1, 0, nullptr);
    }
    for (int p = NPANELS - 1; p >= 0; --p) {
        int colStart = p * NB;
        int nc = NN - colStart;
        larfb_kernel<<<(nc + 63) / 64, LB_BDIM, 0, stream>>>(Q, V, T, p, colStart, 0,
                                                             (p == 0) ? 1 : 0, Qbf);
    }

    gemm_kernel<<<(131072 / BM) * (NN / BN), BDIM, 0, stream>>>(inp, Qbf, out);
}